// Round 7
// baseline (1098.072 us; speedup 1.0000x reference)
//
#include <hip/hip_runtime.h>
#include <stdint.h>

// GIN GNN: N=40000, E=640000, H=128, 5 layers, PROJ=256.
// R7: channel-sliced XCD-affine aggregate — slice=blockIdx%8 maps each
// 16-channel slice to one XCD (h slice 2.56MB + comb slice 128KB fit the
// 4MB XCD L2). 8 edges per wave-load, shuffle-reduce over edge groups.
// Weight swizzles merged into one launch.

typedef unsigned short ushort_t;
typedef unsigned int uint_t;
typedef __attribute__((ext_vector_type(8))) short bf16x8;
typedef __attribute__((ext_vector_type(16))) float f32x16;

#define MFMA32(a, b, c) __builtin_amdgcn_mfma_f32_32x32x16_bf16(a, b, c, 0, 0, 0)

__device__ inline ushort_t f2bf(float f) {
  uint_t u = __builtin_bit_cast(uint_t, f);
  u += 0x7FFFu + ((u >> 16) & 1u);
  return (ushort_t)(u >> 16);
}
__device__ inline float bf2f(uint_t h) {  // low 16 bits
  uint_t u = (h & 0xFFFFu) << 16;
  return __builtin_bit_cast(float, u);
}
__device__ inline uint_t pack2(float a, float b) {
  return (uint_t)f2bf(a) | ((uint_t)f2bf(b) << 16);
}
__device__ inline f32x16 zero16() {
  f32x16 z;
#pragma unroll
  for (int i = 0; i < 16; ++i) z[i] = 0.f;
  return z;
}

// ---------- precompute ----------

// comb[l][c][128] bf16, c = a0|a1<<4|a2<<8
__global__ __launch_bounds__(256) void bond_comb_k(
    const float* __restrict__ bemb, ushort_t* __restrict__ comb)
{
  int idx = blockIdx.x * 256 + threadIdx.x;  // over 5*4096*64
  if (idx >= 5 * 4096 * 64) return;
  int lane = idx & 63, c = (idx >> 6) & 4095, l = idx >> 18;
  const float2* b2 = (const float2*)(bemb + (size_t)l * 3 * 16 * 128);
  float2 e0 = b2[(c & 15) * 64 + lane];
  float2 e1 = b2[(16 + ((c >> 4) & 15)) * 64 + lane];
  float2 e2 = b2[(32 + (c >> 8)) * 64 + lane];
  ((uint_t*)comb)[idx] = pack2(e0.x + e1.x + e2.x, e0.y + e1.y + e2.y);
}

// All 11 weight swizzles in one launch. m<6: K=128,N=256 (w1 x5, linw);
// m>=6: K=256,N=128 (w2 x5).
__global__ __launch_bounds__(256) void swz_all_k(
    const float* __restrict__ w1, const float* __restrict__ linw,
    const float* __restrict__ w2, ushort_t* __restrict__ bswz1,
    ushort_t* __restrict__ bswz2)
{
  int t = blockIdx.x * 256 + threadIdx.x;  // 11*4096
  if (t >= 11 * 4096) return;
  int m = t >> 12, tt = t & 4095, lane = tt & 63;
  if (m < 6) {
    const float* w = (m < 5) ? (w1 + (size_t)m * 32768) : linw;
    ushort_t* o = bswz1 + (size_t)m * 32768;
    int nt = (tt >> 6) & 7, s = tt >> 9;
    int kb = s * 16 + (lane >> 5) * 8, n = nt * 32 + (lane & 31);
    ushort_t tmp[8];
#pragma unroll
    for (int j = 0; j < 8; ++j) tmp[j] = f2bf(w[(size_t)(kb + j) * 256 + n]);
    ((uint4*)o)[tt] = *(uint4*)tmp;
  } else {
    int mm = m - 6;
    const float* w = w2 + (size_t)mm * 32768;
    ushort_t* o = bswz2 + (size_t)mm * 32768;
    int nt = (tt >> 6) & 3, s = tt >> 8;
    int kb = s * 16 + (lane >> 5) * 8, n = nt * 32 + (lane & 31);
    ushort_t tmp[8];
#pragma unroll
    for (int j = 0; j < 8; ++j) tmp[j] = f2bf(w[(size_t)(kb + j) * 128 + n]);
    ((uint4*)o)[tt] = *(uint4*)tmp;
  }
}

// ---------- graph preprocessing ----------

__global__ void zero_int_k(int* p, int n) {
  int i = blockIdx.x * 256 + threadIdx.x;
  if (i < n) p[i] = 0;
}

__global__ void hist_k(const int* __restrict__ ei, int* __restrict__ cnt, int E) {
  int e = blockIdx.x * 256 + threadIdx.x;
  if (e >= E) return;
  atomicAdd(&cnt[ei[E + e]], 1);
}

__global__ __launch_bounds__(256) void block_sum_k(
    const int* __restrict__ cnt, int* __restrict__ bsum, int N)
{
  __shared__ int red[256];
  int t = threadIdx.x, idx = blockIdx.x * 256 + t;
  red[t] = (idx < N) ? cnt[idx] : 0;
  __syncthreads();
  for (int o = 128; o > 0; o >>= 1) {
    if (t < o) red[t] += red[t + o];
    __syncthreads();
  }
  if (t == 0) bsum[blockIdx.x] = red[0];
}

__global__ __launch_bounds__(256) void scan_bsum_k(
    int* __restrict__ bsum, int* __restrict__ rsN, int nb)
{
  __shared__ int s[256];
  int t = threadIdx.x;
  s[t] = (t < nb) ? bsum[t] : 0;
  __syncthreads();
  for (int o = 1; o < 256; o <<= 1) {
    int v = (t >= o) ? s[t - o] : 0;
    __syncthreads();
    s[t] += v;
    __syncthreads();
  }
  if (t < nb) bsum[t] = (t == 0) ? 0 : s[t - 1];
  if (t == nb - 1) *rsN = s[t];
}

__global__ __launch_bounds__(256) void scan_write_k(
    const int* __restrict__ cnt, const int* __restrict__ bsum,
    int* __restrict__ rs, int* __restrict__ cursor, int N)
{
  __shared__ int s[256];
  int t = threadIdx.x, idx = blockIdx.x * 256 + t;
  int v = (idx < N) ? cnt[idx] : 0;
  s[t] = v;
  __syncthreads();
  for (int o = 1; o < 256; o <<= 1) {
    int u = (t >= o) ? s[t - o] : 0;
    __syncthreads();
    s[t] += u;
    __syncthreads();
  }
  int excl = s[t] - v + bsum[blockIdx.x];
  if (idx < N) { rs[idx] = excl; cursor[idx] = excl; }
}

__global__ void scatter_k(const int* __restrict__ ei, const int* __restrict__ ea,
                          int* __restrict__ cursor, uint32_t* __restrict__ sorted, int E)
{
  int e = blockIdx.x * 256 + threadIdx.x;
  if (e >= E) return;
  int src = ei[e], dst = ei[E + e];
  int a0 = ea[e * 3], a1 = ea[e * 3 + 1], a2 = ea[e * 3 + 2];
  int pos = atomicAdd(&cursor[dst], 1);
  sorted[pos] = (uint32_t)src | ((uint32_t)a0 << 16) | ((uint32_t)a1 << 20) | ((uint32_t)a2 << 24);
}

// ---------- node pipeline ----------

__global__ __launch_bounds__(256) void atom_encode_k(
    const int* __restrict__ x, const float* __restrict__ aemb,
    float* __restrict__ raw, int N)
{
  int idx = blockIdx.x * 256 + threadIdx.x;
  if (idx >= N * 64) return;
  int n = idx >> 6, lane = idx & 63;
  const int* xr = x + n * 9;
  float sx = 0.f, sy = 0.f;
#pragma unroll
  for (int f = 0; f < 9; ++f) {
    float2 e = ((const float2*)(aemb + (size_t)(f * 128 + xr[f]) * 128))[lane];
    sx += e.x; sy += e.y;
  }
  ((float2*)raw)[idx] = make_float2(sx, sy);
}

// Channel-sliced aggregate: slice = blockIdx%8 (XCD-affine via %8 dispatch),
// group = blockIdx/8; wave handles node n = group*4+wave, channels
// [slice*16, slice*16+16). Lane: eg = lane>>3 (edge group), c2 = lane&7
// (2 channels). 8 edges per wave iteration, unroll x2, shuffle-reduce.
// Applies prev layer's BN2(+relu) on the fly. Block 0 zeroes stats[0..511].
__global__ __launch_bounds__(256) void aggregate_k(
    const float* __restrict__ raw, const ushort_t* __restrict__ comb,
    const uint32_t* __restrict__ sorted, const int* __restrict__ rs,
    const float* __restrict__ eps, int layer, ushort_t* __restrict__ zin,
    float* __restrict__ stats, const float* __restrict__ stats2,
    const float* __restrict__ g, const float* __restrict__ bb,
    float invN, int N)
{
  if (blockIdx.x == 0) {
    stats[threadIdx.x] = 0.f;
    stats[threadIdx.x + 256] = 0.f;
  }
  int slice = blockIdx.x & 7, group = blockIdx.x >> 3;
  int wave = threadIdx.x >> 6, lane = threadIdx.x & 63;
  int n = group * 4 + wave;
  if (n >= N) return;
  int eg = lane >> 3, c2 = lane & 7;
  int soff = slice * 8 + c2;            // float2/uint index within a row of 64
  int ch0 = soff * 2;                   // absolute even channel
  float scx = 1.f, scy = 1.f, shx = 0.f, shy = 0.f;
  const bool bn = (stats2 != nullptr);
  if (bn) {
    float mu0 = stats2[ch0] * invN, mu1 = stats2[ch0 + 1] * invN;
    float v0 = stats2[128 + ch0] * invN - mu0 * mu0;
    float v1 = stats2[128 + ch0 + 1] * invN - mu1 * mu1;
    scx = rsqrtf(v0 + 1e-5f) * g[ch0];
    scy = rsqrtf(v1 + 1e-5f) * g[ch0 + 1];
    shx = bb[ch0] - mu0 * scx;
    shy = bb[ch0 + 1] - mu1 * scy;
  }
  int beg = rs[n], end = rs[n + 1];
  const float2* h2 = (const float2*)raw;                  // row stride 64
  const uint_t* cb = ((const uint_t*)comb) + (size_t)layer * 4096 * 64;
  float ax = 0.f, ay = 0.f;
  int i = beg + eg;
  // unroll x2: 16 edges in flight per wave
  for (; i + 8 < end; i += 16) {
    uint32_t p0 = sorted[i], p1 = sorted[i + 8];
    float2 hv0 = h2[(size_t)(p0 & 0xFFFFu) * 64 + soff];
    uint_t ee0 = cb[(p0 >> 16) * 64 + soff];
    float2 hv1 = h2[(size_t)(p1 & 0xFFFFu) * 64 + soff];
    uint_t ee1 = cb[(p1 >> 16) * 64 + soff];
    float h0x = hv0.x, h0y = hv0.y, h1x = hv1.x, h1y = hv1.y;
    if (bn) {
      h0x = fmaxf(fmaf(h0x, scx, shx), 0.f);
      h0y = fmaxf(fmaf(h0y, scy, shy), 0.f);
      h1x = fmaxf(fmaf(h1x, scx, shx), 0.f);
      h1y = fmaxf(fmaf(h1y, scy, shy), 0.f);
    }
    ax += fmaxf(h0x + bf2f(ee0), 0.f) + fmaxf(h1x + bf2f(ee1), 0.f);
    ay += fmaxf(h0y + bf2f(ee0 >> 16), 0.f) + fmaxf(h1y + bf2f(ee1 >> 16), 0.f);
  }
  if (i < end) {
    uint32_t p = sorted[i];
    float2 hv = h2[(size_t)(p & 0xFFFFu) * 64 + soff];
    uint_t ee = cb[(p >> 16) * 64 + soff];
    float hx = hv.x, hy = hv.y;
    if (bn) {
      hx = fmaxf(fmaf(hx, scx, shx), 0.f);
      hy = fmaxf(fmaf(hy, scy, shy), 0.f);
    }
    ax += fmaxf(hx + bf2f(ee), 0.f);
    ay += fmaxf(hy + bf2f(ee >> 16), 0.f);
  }
  // reduce across the 8 edge groups
  ax += __shfl_xor(ax, 8);  ay += __shfl_xor(ay, 8);
  ax += __shfl_xor(ax, 16); ay += __shfl_xor(ay, 16);
  ax += __shfl_xor(ax, 32); ay += __shfl_xor(ay, 32);
  float s = 1.f + eps[layer];
  float2 hn = h2[(size_t)n * 64 + soff];
  float hx = hn.x, hy = hn.y;
  if (bn) {
    hx = fmaxf(fmaf(hx, scx, shx), 0.f);
    hy = fmaxf(fmaf(hy, scy, shy), 0.f);
  }
  if (eg == 0)
    ((uint_t*)zin)[(size_t)n * 64 + soff] = pack2(fmaf(s, hx, ax), fmaf(s, hy, ay));
}

// ---------- MFMA GEMMs ----------
// A staged in LDS, XOR-swizzled in 16B chunks: elem (r,k) at col
// ((k>>3)^(r&15))*8 + (k&7).   Frags: A[m=lane&31][k=(lane>>5)*8+j],
// B[k][n=lane&31][k=(lane>>5)*8+j] (pre-swizzled),
// C/D col=lane&31, row=(reg&3)+8*(reg>>2)+4*(lane>>5).

// Kernel A: GEMM1 [64,128]@[128,256]+b1, emits ONLY column sum/sumsq into
// statsOut (BN1 accums). Block 0 zeroes stats2 region (256 floats).
__global__ __launch_bounds__(256) void gemm1_stats_k(
    const ushort_t* __restrict__ in, const ushort_t* __restrict__ bswz,
    const float* __restrict__ bias, float* __restrict__ statsOut,
    float* __restrict__ zeroPtr)
{
  __shared__ ushort_t As[64 * 128];
  int tid = threadIdx.x;
  int wave = tid >> 6, lane = tid & 63;
  int lr = lane & 31, half = lane >> 5;
  int row0 = blockIdx.x * 64;
  if (blockIdx.x == 0) zeroPtr[tid] = 0.f;
  {
    const uint2* src = (const uint2*)(in + (size_t)row0 * 128);
#pragma unroll
    for (int i = 0; i < 8; ++i) {
      int idx = tid + 256 * i;
      int r = idx >> 5, c = (idx & 31) * 4;
      uint2 v = src[idx];
      int scol = (((c >> 3) ^ (r & 15)) << 3) | (c & 7);
      *(uint2*)&As[r * 128 + scol] = v;
    }
  }
  __syncthreads();
  int nt0 = wave * 2, nt1 = nt0 + 1;
  f32x16 acc00 = zero16(), acc01 = zero16(), acc10 = zero16(), acc11 = zero16();
  const bf16x8* Bp = (const bf16x8*)bswz;
#pragma unroll
  for (int s = 0; s < 8; ++s) {
    int k = s * 16 + half * 8;
    int scol = ((k >> 3) ^ (lr & 15)) << 3;
    bf16x8 a0 = *(const bf16x8*)&As[lr * 128 + scol];
    bf16x8 a1 = *(const bf16x8*)&As[(32 + lr) * 128 + scol];
    bf16x8 b0 = Bp[(s * 8 + nt0) * 64 + lane];
    bf16x8 b1 = Bp[(s * 8 + nt1) * 64 + lane];
    acc00 = MFMA32(a0, b0, acc00);
    acc10 = MFMA32(a1, b0, acc10);
    acc01 = MFMA32(a0, b1, acc01);
    acc11 = MFMA32(a1, b1, acc11);
  }
  int col0 = nt0 * 32 + lr, col1 = nt1 * 32 + lr;
  float bv0 = bias[col0], bv1 = bias[col1];
  float s0 = 0, q0 = 0, s1 = 0, q1 = 0;
#pragma unroll
  for (int r2 = 0; r2 < 16; ++r2) {
    float v00 = acc00[r2] + bv0, v10 = acc10[r2] + bv0;
    float v01 = acc01[r2] + bv1, v11 = acc11[r2] + bv1;
    s0 += v00 + v10; q0 += v00 * v00 + v10 * v10;
    s1 += v01 + v11; q1 += v01 * v01 + v11 * v11;
  }
  s0 += __shfl_xor(s0, 32); q0 += __shfl_xor(q0, 32);
  s1 += __shfl_xor(s1, 32); q1 += __shfl_xor(q1, 32);
  if (lane < 32) {
    atomicAdd(&statsOut[col0], s0);
    atomicAdd(&statsOut[256 + col0], q0);
    atomicAdd(&statsOut[col1], s1);
    atomicAdd(&statsOut[256 + col1], q1);
  }
}

// Kernel B: recompute GEMM1, BN1+relu in-register (b1 folded into shift),
// C->A relayout via LDS (bf16), GEMM2 [64,256]@[256,128]+b2 -> raw fp32,
// accumulate BN2 stats.
__global__ __launch_bounds__(256) void fused_mlp_k(
    const ushort_t* __restrict__ in, const ushort_t* __restrict__ bswz1,
    const float* __restrict__ b1, const float* __restrict__ stats1,
    const float* __restrict__ g1, const float* __restrict__ bb1,
    const ushort_t* __restrict__ bswz2, const float* __restrict__ b2,
    float* __restrict__ outf, float* __restrict__ stats2, float invN)
{
  __shared__ ushort_t As[64 * 128];   // zin staging (16 KB)
  __shared__ ushort_t Bs[64 * 256];   // post-BN1 z1 tile (32 KB)
  __shared__ float sc1[256], sh1[256];
  int tid = threadIdx.x;
  int wave = tid >> 6, lane = tid & 63;
  int lr = lane & 31, half = lane >> 5;
  int row0 = blockIdx.x * 64;
  {
    int c = tid;
    float mu = stats1[c] * invN;
    float var = stats1[256 + c] * invN - mu * mu;
    float r = rsqrtf(var + 1e-5f) * g1[c];
    sc1[c] = r;
    sh1[c] = bb1[c] - mu * r + b1[c] * r;   // fold bias1 into shift
  }
  {
    const uint2* src = (const uint2*)(in + (size_t)row0 * 128);
#pragma unroll
    for (int i = 0; i < 8; ++i) {
      int idx = tid + 256 * i;
      int r = idx >> 5, c = (idx & 31) * 4;
      uint2 v = src[idx];
      int scol = (((c >> 3) ^ (r & 15)) << 3) | (c & 7);
      *(uint2*)&As[r * 128 + scol] = v;
    }
  }
  __syncthreads();
  int nt0 = wave * 2, nt1 = nt0 + 1;
  f32x16 acc00 = zero16(), acc01 = zero16(), acc10 = zero16(), acc11 = zero16();
  {
    const bf16x8* Bp = (const bf16x8*)bswz1;
#pragma unroll
    for (int s = 0; s < 8; ++s) {
      int k = s * 16 + half * 8;
      int scol = ((k >> 3) ^ (lr & 15)) << 3;
      bf16x8 a0 = *(const bf16x8*)&As[lr * 128 + scol];
      bf16x8 a1 = *(const bf16x8*)&As[(32 + lr) * 128 + scol];
      bf16x8 b0v = Bp[(s * 8 + nt0) * 64 + lane];
      bf16x8 b1v = Bp[(s * 8 + nt1) * 64 + lane];
      acc00 = MFMA32(a0, b0v, acc00);
      acc10 = MFMA32(a1, b0v, acc10);
      acc01 = MFMA32(a0, b1v, acc01);
      acc11 = MFMA32(a1, b1v, acc11);
    }
  }
  {
    int col0 = nt0 * 32 + lr, col1 = nt1 * 32 + lr;
    float sc0v = sc1[col0], sh0v = sh1[col0];
    float sc1v = sc1[col1], sh1v = sh1[col1];
    auto wr = [&](const f32x16& a, int mtb, int col, float scv, float shv) {
#pragma unroll
      for (int r2 = 0; r2 < 16; ++r2) {
        int row = mtb + (r2 & 3) + 8 * (r2 >> 2) + 4 * half;
        float v = fmaxf(fmaf(a[r2], scv, shv), 0.f);
        int scol = (((col >> 3) ^ (row & 15)) << 3) | (col & 7);
        Bs[row * 256 + scol] = f2bf(v);
      }
    };
    wr(acc00, 0, col0, sc0v, sh0v);
    wr(acc10, 32, col0, sc0v, sh0v);
    wr(acc01, 0, col1, sc1v, sh1v);
    wr(acc11, 32, col1, sc1v, sh1v);
  }
  __syncthreads();
  f32x16 acc0 = zero16(), acc1 = zero16();
  {
    const bf16x8* Bp2 = (const bf16x8*)bswz2;
#pragma unroll
    for (int s = 0; s < 16; ++s) {
      int k = s * 16 + half * 8;
      int scol = ((k >> 3) ^ (lr & 15)) << 3;
      bf16x8 a0 = *(const bf16x8*)&Bs[lr * 256 + scol];
      bf16x8 a1 = *(const bf16x8*)&Bs[(32 + lr) * 256 + scol];
      bf16x8 b = Bp2[(s * 4 + wave) * 64 + lane];
      acc0 = MFMA32(a0, b, acc0);
      acc1 = MFMA32(a1, b, acc1);
    }
  }
  int col = wave * 32 + lr;
  float bv = b2[col];
  float s0 = 0, q0 = 0;
  auto emit = [&](const f32x16& a, int mtb) {
#pragma unroll
    for (int r2 = 0; r2 < 16; ++r2) {
      int row = row0 + mtb + (r2 & 3) + 8 * (r2 >> 2) + 4 * half;
      float v = a[r2] + bv;
      outf[(size_t)row * 128 + col] = v;
      s0 += v;
      q0 += v * v;
    }
  };
  emit(acc0, 0);
  emit(acc1, 32);
  s0 += __shfl_xor(s0, 32);
  q0 += __shfl_xor(q0, 32);
  if (lane < 32) {
    atomicAdd(&stats2[col], s0);
    atomicAdd(&stats2[128 + col], q0);
  }
}

// Final projection: BN(stats2) on fp32 raw at load (no relu), then
// [64,128]@[128,256]+linb -> fp32 out.
__global__ __launch_bounds__(256) void final_proj_k(
    const float* __restrict__ inf, const ushort_t* __restrict__ bswz,
    const float* __restrict__ bias, const float* __restrict__ stats2,
    const float* __restrict__ g, const float* __restrict__ bb,
    float* __restrict__ outf, float invN)
{
  __shared__ ushort_t As[64 * 128];
  __shared__ float sc[128], sh[128];
  int tid = threadIdx.x;
  int wave = tid >> 6, lane = tid & 63;
  int lr = lane & 31, half = lane >> 5;
  int row0 = blockIdx.x * 64;
  if (tid < 128) {
    int c = tid;
    float mu = stats2[c] * invN;
    float var = stats2[128 + c] * invN - mu * mu;
    float r = rsqrtf(var + 1e-5f) * g[c];
    sc[c] = r;
    sh[c] = bb[c] - mu * r;
  }
  __syncthreads();
  {
    const float4* src = (const float4*)(inf + (size_t)row0 * 128);
#pragma unroll
    for (int i = 0; i < 8; ++i) {
      int idx = tid + 256 * i;
      int r = idx >> 5, c = (idx & 31) * 4;
      float4 v = src[idx];
      v.x = fmaf(v.x, sc[c], sh[c]);
      v.y = fmaf(v.y, sc[c + 1], sh[c + 1]);
      v.z = fmaf(v.z, sc[c + 2], sh[c + 2]);
      v.w = fmaf(v.w, sc[c + 3], sh[c + 3]);
      uint2 o;
      o.x = pack2(v.x, v.y);
      o.y = pack2(v.z, v.w);
      int scol = (((c >> 3) ^ (r & 15)) << 3) | (c & 7);
      *(uint2*)&As[r * 128 + scol] = o;
    }
  }
  __syncthreads();
  int nt0 = wave * 2, nt1 = nt0 + 1;
  f32x16 acc00 = zero16(), acc01 = zero16(), acc10 = zero16(), acc11 = zero16();
  const bf16x8* Bp = (const bf16x8*)bswz;
#pragma unroll
  for (int s = 0; s < 8; ++s) {
    int k = s * 16 + half * 8;
    int scol = ((k >> 3) ^ (lr & 15)) << 3;
    bf16x8 a0 = *(const bf16x8*)&As[lr * 128 + scol];
    bf16x8 a1 = *(const bf16x8*)&As[(32 + lr) * 128 + scol];
    bf16x8 b0 = Bp[(s * 8 + nt0) * 64 + lane];
    bf16x8 b1 = Bp[(s * 8 + nt1) * 64 + lane];
    acc00 = MFMA32(a0, b0, acc00);
    acc10 = MFMA32(a1, b0, acc10);
    acc01 = MFMA32(a0, b1, acc01);
    acc11 = MFMA32(a1, b1, acc11);
  }
  int col0 = nt0 * 32 + lr, col1 = nt1 * 32 + lr;
  float bv0 = bias[col0], bv1 = bias[col1];
  auto emit = [&](const f32x16& a, int mtb, int col, float bv) {
#pragma unroll
    for (int r2 = 0; r2 < 16; ++r2) {
      int row = row0 + mtb + (r2 & 3) + 8 * (r2 >> 2) + 4 * half;
      outf[(size_t)row * 256 + col] = a[r2] + bv;
    }
  };
  emit(acc00, 0, col0, bv0);
  emit(acc10, 32, col0, bv0);
  emit(acc01, 0, col1, bv1);
  emit(acc11, 32, col1, bv1);
}

extern "C" void kernel_launch(void* const* d_in, const int* in_sizes, int n_in,
                              void* d_out, int out_size, void* d_ws, size_t ws_size,
                              hipStream_t stream)
{
  const int* x = (const int*)d_in[0];
  const int* ei = (const int*)d_in[1];
  const int* ea = (const int*)d_in[2];
  const float* aemb = (const float*)d_in[3];
  const float* bemb = (const float*)d_in[4];
  const float* eps = (const float*)d_in[5];
  const float* w1 = (const float*)d_in[6];
  const float* b1 = (const float*)d_in[7];
  const float* bn1g = (const float*)d_in[8];
  const float* bn1b = (const float*)d_in[9];
  const float* w2 = (const float*)d_in[10];
  const float* b2 = (const float*)d_in[11];
  const float* bng = (const float*)d_in[12];
  const float* bnb = (const float*)d_in[13];
  const float* linw = (const float*)d_in[14];
  const float* linb = (const float*)d_in[15];
  int N = in_sizes[0] / 9;   // 40000
  int E = in_sizes[1] / 2;   // 640000
  int nb = (N + 255) / 256;

  char* ws = (char*)d_ws;
  size_t off = 0;
  auto alloc = [&](size_t bytes) {
    void* p = ws + off;
    off += (bytes + 255) & ~(size_t)255;
    return p;
  };
  float* raw = (float*)alloc((size_t)N * 128 * 4);         // pre-BN h, fp32
  ushort_t* zin = (ushort_t*)alloc((size_t)N * 128 * 2);   // GEMM1 input, bf16
  ushort_t* comb = (ushort_t*)alloc((size_t)5 * 4096 * 128 * 2);
  ushort_t* bswz1 = (ushort_t*)alloc((size_t)6 * 32768 * 2);  // 5x w1 + linw
  ushort_t* bswz2 = (ushort_t*)alloc((size_t)5 * 32768 * 2);
  uint32_t* sorted = (uint32_t*)alloc((size_t)E * 4);
  int* rs = (int*)alloc((size_t)(N + 1) * 4);
  int* cursor = (int*)alloc((size_t)N * 4);
  int* cnt = (int*)alloc((size_t)N * 4);
  int* bsum = (int*)alloc((size_t)nb * 4);
  float* stats = (float*)alloc(768 * 4);  // [sum1:256][sq1:256][sum2:128][sq2:128]
  float invN = 1.f / (float)N;

  bond_comb_k<<<(5 * 4096 * 64 + 255) / 256, 256, 0, stream>>>(bemb, comb);
  swz_all_k<<<(11 * 4096 + 255) / 256, 256, 0, stream>>>(w1, linw, w2, bswz1, bswz2);

  atom_encode_k<<<(N * 64 + 255) / 256, 256, 0, stream>>>(x, aemb, raw, N);
  zero_int_k<<<(N + 255) / 256, 256, 0, stream>>>(cnt, N);
  hist_k<<<(E + 255) / 256, 256, 0, stream>>>(ei, cnt, E);
  block_sum_k<<<nb, 256, 0, stream>>>(cnt, bsum, N);
  scan_bsum_k<<<1, 256, 0, stream>>>(bsum, rs + N, nb);
  scan_write_k<<<nb, 256, 0, stream>>>(cnt, bsum, rs, cursor, N);
  scatter_k<<<(E + 255) / 256, 256, 0, stream>>>(ei, ea, cursor, sorted, E);

  for (int l = 0; l < 5; ++l) {
    const float* st2 = (l == 0) ? nullptr : stats + 512;
    const float* gg  = (l == 0) ? nullptr : bng + (size_t)(l - 1) * 128;
    const float* bbb = (l == 0) ? nullptr : bnb + (size_t)(l - 1) * 128;
    aggregate_k<<<8 * ((N + 3) / 4), 256, 0, stream>>>(
        raw, comb, sorted, rs, eps, l, zin, stats, st2, gg, bbb, invN, N);
    gemm1_stats_k<<<N / 64, 256, 0, stream>>>(
        zin, bswz1 + (size_t)l * 32768, b1 + (size_t)l * 256,
        stats, stats + 512);
    fused_mlp_k<<<N / 64, 256, 0, stream>>>(
        zin, bswz1 + (size_t)l * 32768, b1 + (size_t)l * 256,
        stats, bn1g + (size_t)l * 256, bn1b + (size_t)l * 256,
        bswz2 + (size_t)l * 32768, b2 + (size_t)l * 128,
        raw, stats + 512, invN);
  }
  final_proj_k<<<N / 64, 256, 0, stream>>>(
      raw, bswz1 + (size_t)5 * 32768, linb, stats + 512,
      bng + (size_t)4 * 128, bnb + (size_t)4 * 128, (float*)d_out, invN);
}

// Round 8
// 712.015 us; speedup vs baseline: 1.5422x; 1.5422x over previous
//
#include <hip/hip_runtime.h>
#include <stdint.h>

// GIN GNN: N=40000, E=640000, H=128, 5 layers, PROJ=256.
// R8: R7's channel-sliced aggregate REVERTED (sub-line 64B gathers wasted
// fabric: 146MB fetch at 1.1TB/s, VGPR 12 = no MLP). Back to R6 full-row
// wave gathers, pipeline widened 8->16 edges in flight.

typedef unsigned short ushort_t;
typedef unsigned int uint_t;
typedef __attribute__((ext_vector_type(8))) short bf16x8;
typedef __attribute__((ext_vector_type(16))) float f32x16;

#define MFMA32(a, b, c) __builtin_amdgcn_mfma_f32_32x32x16_bf16(a, b, c, 0, 0, 0)

__device__ inline ushort_t f2bf(float f) {
  uint_t u = __builtin_bit_cast(uint_t, f);
  u += 0x7FFFu + ((u >> 16) & 1u);
  return (ushort_t)(u >> 16);
}
__device__ inline float bf2f(uint_t h) {  // low 16 bits
  uint_t u = (h & 0xFFFFu) << 16;
  return __builtin_bit_cast(float, u);
}
__device__ inline uint_t pack2(float a, float b) {
  return (uint_t)f2bf(a) | ((uint_t)f2bf(b) << 16);
}
__device__ inline f32x16 zero16() {
  f32x16 z;
#pragma unroll
  for (int i = 0; i < 16; ++i) z[i] = 0.f;
  return z;
}

// ---------- precompute ----------

// comb[l][c][128] bf16, c = a0|a1<<4|a2<<8
__global__ __launch_bounds__(256) void bond_comb_k(
    const float* __restrict__ bemb, ushort_t* __restrict__ comb)
{
  int idx = blockIdx.x * 256 + threadIdx.x;  // over 5*4096*64
  if (idx >= 5 * 4096 * 64) return;
  int lane = idx & 63, c = (idx >> 6) & 4095, l = idx >> 18;
  const float2* b2 = (const float2*)(bemb + (size_t)l * 3 * 16 * 128);
  float2 e0 = b2[(c & 15) * 64 + lane];
  float2 e1 = b2[(16 + ((c >> 4) & 15)) * 64 + lane];
  float2 e2 = b2[(32 + (c >> 8)) * 64 + lane];
  ((uint_t*)comb)[idx] = pack2(e0.x + e1.x + e2.x, e0.y + e1.y + e2.y);
}

// All 11 weight swizzles in one launch. m<6: K=128,N=256 (w1 x5, linw);
// m>=6: K=256,N=128 (w2 x5).
__global__ __launch_bounds__(256) void swz_all_k(
    const float* __restrict__ w1, const float* __restrict__ linw,
    const float* __restrict__ w2, ushort_t* __restrict__ bswz1,
    ushort_t* __restrict__ bswz2)
{
  int t = blockIdx.x * 256 + threadIdx.x;  // 11*4096
  if (t >= 11 * 4096) return;
  int m = t >> 12, tt = t & 4095, lane = tt & 63;
  if (m < 6) {
    const float* w = (m < 5) ? (w1 + (size_t)m * 32768) : linw;
    ushort_t* o = bswz1 + (size_t)m * 32768;
    int nt = (tt >> 6) & 7, s = tt >> 9;
    int kb = s * 16 + (lane >> 5) * 8, n = nt * 32 + (lane & 31);
    ushort_t tmp[8];
#pragma unroll
    for (int j = 0; j < 8; ++j) tmp[j] = f2bf(w[(size_t)(kb + j) * 256 + n]);
    ((uint4*)o)[tt] = *(uint4*)tmp;
  } else {
    int mm = m - 6;
    const float* w = w2 + (size_t)mm * 32768;
    ushort_t* o = bswz2 + (size_t)mm * 32768;
    int nt = (tt >> 6) & 3, s = tt >> 8;
    int kb = s * 16 + (lane >> 5) * 8, n = nt * 32 + (lane & 31);
    ushort_t tmp[8];
#pragma unroll
    for (int j = 0; j < 8; ++j) tmp[j] = f2bf(w[(size_t)(kb + j) * 128 + n]);
    ((uint4*)o)[tt] = *(uint4*)tmp;
  }
}

// ---------- graph preprocessing ----------

__global__ void zero_int_k(int* p, int n) {
  int i = blockIdx.x * 256 + threadIdx.x;
  if (i < n) p[i] = 0;
}

__global__ void hist_k(const int* __restrict__ ei, int* __restrict__ cnt, int E) {
  int e = blockIdx.x * 256 + threadIdx.x;
  if (e >= E) return;
  atomicAdd(&cnt[ei[E + e]], 1);
}

__global__ __launch_bounds__(256) void block_sum_k(
    const int* __restrict__ cnt, int* __restrict__ bsum, int N)
{
  __shared__ int red[256];
  int t = threadIdx.x, idx = blockIdx.x * 256 + t;
  red[t] = (idx < N) ? cnt[idx] : 0;
  __syncthreads();
  for (int o = 128; o > 0; o >>= 1) {
    if (t < o) red[t] += red[t + o];
    __syncthreads();
  }
  if (t == 0) bsum[blockIdx.x] = red[0];
}

__global__ __launch_bounds__(256) void scan_bsum_k(
    int* __restrict__ bsum, int* __restrict__ rsN, int nb)
{
  __shared__ int s[256];
  int t = threadIdx.x;
  s[t] = (t < nb) ? bsum[t] : 0;
  __syncthreads();
  for (int o = 1; o < 256; o <<= 1) {
    int v = (t >= o) ? s[t - o] : 0;
    __syncthreads();
    s[t] += v;
    __syncthreads();
  }
  if (t < nb) bsum[t] = (t == 0) ? 0 : s[t - 1];
  if (t == nb - 1) *rsN = s[t];
}

__global__ __launch_bounds__(256) void scan_write_k(
    const int* __restrict__ cnt, const int* __restrict__ bsum,
    int* __restrict__ rs, int* __restrict__ cursor, int N)
{
  __shared__ int s[256];
  int t = threadIdx.x, idx = blockIdx.x * 256 + t;
  int v = (idx < N) ? cnt[idx] : 0;
  s[t] = v;
  __syncthreads();
  for (int o = 1; o < 256; o <<= 1) {
    int u = (t >= o) ? s[t - o] : 0;
    __syncthreads();
    s[t] += u;
    __syncthreads();
  }
  int excl = s[t] - v + bsum[blockIdx.x];
  if (idx < N) { rs[idx] = excl; cursor[idx] = excl; }
}

__global__ void scatter_k(const int* __restrict__ ei, const int* __restrict__ ea,
                          int* __restrict__ cursor, uint32_t* __restrict__ sorted, int E)
{
  int e = blockIdx.x * 256 + threadIdx.x;
  if (e >= E) return;
  int src = ei[e], dst = ei[E + e];
  int a0 = ea[e * 3], a1 = ea[e * 3 + 1], a2 = ea[e * 3 + 2];
  int pos = atomicAdd(&cursor[dst], 1);
  sorted[pos] = (uint32_t)src | ((uint32_t)a0 << 16) | ((uint32_t)a1 << 20) | ((uint32_t)a2 << 24);
}

// ---------- node pipeline ----------

__global__ __launch_bounds__(256) void atom_encode_k(
    const int* __restrict__ x, const float* __restrict__ aemb,
    float* __restrict__ raw, int N)
{
  int idx = blockIdx.x * 256 + threadIdx.x;
  if (idx >= N * 64) return;
  int n = idx >> 6, lane = idx & 63;
  const int* xr = x + n * 9;
  float sx = 0.f, sy = 0.f;
#pragma unroll
  for (int f = 0; f < 9; ++f) {
    float2 e = ((const float2*)(aemb + (size_t)(f * 128 + xr[f]) * 128))[lane];
    sx += e.x; sy += e.y;
  }
  ((float2*)raw)[idx] = make_float2(sx, sy);
}

// One wave per node; full 512B-row gathers; applies prev layer's BN2(+relu)
// on the fly. zin(bf16) = (1+eps)*hbn + sum_e relu(hbn[src] + comb[c]).
// Edge loop pipelined x16 (all 33 loads issued before first consume).
// Block 0 zeroes stats[0..511] (BN1 accums).
__global__ __launch_bounds__(256) void aggregate_k(
    const float* __restrict__ raw, const ushort_t* __restrict__ comb,
    const uint32_t* __restrict__ sorted, const int* __restrict__ rs,
    const float* __restrict__ eps, int layer, ushort_t* __restrict__ zin,
    float* __restrict__ stats, const float* __restrict__ stats2,
    const float* __restrict__ g, const float* __restrict__ bb,
    float invN, int N)
{
  if (blockIdx.x == 0) {
    stats[threadIdx.x] = 0.f;
    stats[threadIdx.x + 256] = 0.f;
  }
  int wave = threadIdx.x >> 6, lane = threadIdx.x & 63;
  int n = blockIdx.x * 4 + wave;
  if (n >= N) return;
  float scx = 1.f, scy = 1.f, shx = 0.f, shy = 0.f;
  const bool bn = (stats2 != nullptr);
  if (bn) {
    int c0 = 2 * lane, c1 = c0 + 1;
    float mu0 = stats2[c0] * invN, mu1 = stats2[c1] * invN;
    float v0 = stats2[128 + c0] * invN - mu0 * mu0;
    float v1 = stats2[128 + c1] * invN - mu1 * mu1;
    scx = rsqrtf(v0 + 1e-5f) * g[c0];
    scy = rsqrtf(v1 + 1e-5f) * g[c1];
    shx = bb[c0] - mu0 * scx;
    shy = bb[c1] - mu1 * scy;
  }
  int beg = rs[n], end = rs[n + 1];
  const float2* h2 = (const float2*)raw;
  const uint_t* cb = ((const uint_t*)comb) + (size_t)layer * 4096 * 64;
  float ax = 0.f, ay = 0.f;
  int i = beg;
  for (; i + 16 <= end; i += 16) {
    uint32_t p[16];
#pragma unroll
    for (int j = 0; j < 16; ++j) p[j] = sorted[i + j];
    float2 hv[16];
    uint_t ee[16];
#pragma unroll
    for (int j = 0; j < 16; ++j) {
      hv[j] = h2[(size_t)(p[j] & 0xFFFFu) * 64 + lane];
      ee[j] = cb[(p[j] >> 16) * 64 + lane];
    }
#pragma unroll
    for (int j = 0; j < 16; ++j) {
      float hx = hv[j].x, hy = hv[j].y;
      if (bn) {
        hx = fmaxf(fmaf(hx, scx, shx), 0.f);
        hy = fmaxf(fmaf(hy, scy, shy), 0.f);
      }
      ax += fmaxf(hx + bf2f(ee[j]), 0.f);
      ay += fmaxf(hy + bf2f(ee[j] >> 16), 0.f);
    }
  }
  for (; i + 4 <= end; i += 4) {
    uint32_t p[4];
#pragma unroll
    for (int j = 0; j < 4; ++j) p[j] = sorted[i + j];
    float2 hv[4];
    uint_t ee[4];
#pragma unroll
    for (int j = 0; j < 4; ++j) {
      hv[j] = h2[(size_t)(p[j] & 0xFFFFu) * 64 + lane];
      ee[j] = cb[(p[j] >> 16) * 64 + lane];
    }
#pragma unroll
    for (int j = 0; j < 4; ++j) {
      float hx = hv[j].x, hy = hv[j].y;
      if (bn) {
        hx = fmaxf(fmaf(hx, scx, shx), 0.f);
        hy = fmaxf(fmaf(hy, scy, shy), 0.f);
      }
      ax += fmaxf(hx + bf2f(ee[j]), 0.f);
      ay += fmaxf(hy + bf2f(ee[j] >> 16), 0.f);
    }
  }
  for (; i < end; ++i) {
    uint32_t p = sorted[i];
    uint_t ee = cb[(p >> 16) * 64 + lane];
    float2 hv = h2[(size_t)(p & 0xFFFFu) * 64 + lane];
    if (bn) {
      hv.x = fmaxf(fmaf(hv.x, scx, shx), 0.f);
      hv.y = fmaxf(fmaf(hv.y, scy, shy), 0.f);
    }
    ax += fmaxf(hv.x + bf2f(ee), 0.f);
    ay += fmaxf(hv.y + bf2f(ee >> 16), 0.f);
  }
  float s = 1.f + eps[layer];
  float2 hn = h2[(size_t)n * 64 + lane];
  float hx = hn.x, hy = hn.y;
  if (bn) {
    hx = fmaxf(fmaf(hx, scx, shx), 0.f);
    hy = fmaxf(fmaf(hy, scy, shy), 0.f);
  }
  ((uint_t*)zin)[(size_t)n * 64 + lane] = pack2(fmaf(s, hx, ax), fmaf(s, hy, ay));
}

// ---------- MFMA GEMMs ----------
// A staged in LDS, XOR-swizzled in 16B chunks: elem (r,k) at col
// ((k>>3)^(r&15))*8 + (k&7).   Frags: A[m=lane&31][k=(lane>>5)*8+j],
// B[k][n=lane&31][k=(lane>>5)*8+j] (pre-swizzled),
// C/D col=lane&31, row=(reg&3)+8*(reg>>2)+4*(lane>>5).

// Kernel A: GEMM1 [64,128]@[128,256]+b1, emits ONLY column sum/sumsq into
// statsOut (BN1 accums). Block 0 zeroes stats2 region (256 floats).
__global__ __launch_bounds__(256) void gemm1_stats_k(
    const ushort_t* __restrict__ in, const ushort_t* __restrict__ bswz,
    const float* __restrict__ bias, float* __restrict__ statsOut,
    float* __restrict__ zeroPtr)
{
  __shared__ ushort_t As[64 * 128];
  int tid = threadIdx.x;
  int wave = tid >> 6, lane = tid & 63;
  int lr = lane & 31, half = lane >> 5;
  int row0 = blockIdx.x * 64;
  if (blockIdx.x == 0) zeroPtr[tid] = 0.f;
  {
    const uint2* src = (const uint2*)(in + (size_t)row0 * 128);
#pragma unroll
    for (int i = 0; i < 8; ++i) {
      int idx = tid + 256 * i;
      int r = idx >> 5, c = (idx & 31) * 4;
      uint2 v = src[idx];
      int scol = (((c >> 3) ^ (r & 15)) << 3) | (c & 7);
      *(uint2*)&As[r * 128 + scol] = v;
    }
  }
  __syncthreads();
  int nt0 = wave * 2, nt1 = nt0 + 1;
  f32x16 acc00 = zero16(), acc01 = zero16(), acc10 = zero16(), acc11 = zero16();
  const bf16x8* Bp = (const bf16x8*)bswz;
#pragma unroll
  for (int s = 0; s < 8; ++s) {
    int k = s * 16 + half * 8;
    int scol = ((k >> 3) ^ (lr & 15)) << 3;
    bf16x8 a0 = *(const bf16x8*)&As[lr * 128 + scol];
    bf16x8 a1 = *(const bf16x8*)&As[(32 + lr) * 128 + scol];
    bf16x8 b0 = Bp[(s * 8 + nt0) * 64 + lane];
    bf16x8 b1 = Bp[(s * 8 + nt1) * 64 + lane];
    acc00 = MFMA32(a0, b0, acc00);
    acc10 = MFMA32(a1, b0, acc10);
    acc01 = MFMA32(a0, b1, acc01);
    acc11 = MFMA32(a1, b1, acc11);
  }
  int col0 = nt0 * 32 + lr, col1 = nt1 * 32 + lr;
  float bv0 = bias[col0], bv1 = bias[col1];
  float s0 = 0, q0 = 0, s1 = 0, q1 = 0;
#pragma unroll
  for (int r2 = 0; r2 < 16; ++r2) {
    float v00 = acc00[r2] + bv0, v10 = acc10[r2] + bv0;
    float v01 = acc01[r2] + bv1, v11 = acc11[r2] + bv1;
    s0 += v00 + v10; q0 += v00 * v00 + v10 * v10;
    s1 += v01 + v11; q1 += v01 * v01 + v11 * v11;
  }
  s0 += __shfl_xor(s0, 32); q0 += __shfl_xor(q0, 32);
  s1 += __shfl_xor(s1, 32); q1 += __shfl_xor(q1, 32);
  if (lane < 32) {
    atomicAdd(&statsOut[col0], s0);
    atomicAdd(&statsOut[256 + col0], q0);
    atomicAdd(&statsOut[col1], s1);
    atomicAdd(&statsOut[256 + col1], q1);
  }
}

// Kernel B: recompute GEMM1, BN1+relu in-register (b1 folded into shift),
// C->A relayout via LDS (bf16), GEMM2 [64,256]@[256,128]+b2 -> raw fp32,
// accumulate BN2 stats.
__global__ __launch_bounds__(256) void fused_mlp_k(
    const ushort_t* __restrict__ in, const ushort_t* __restrict__ bswz1,
    const float* __restrict__ b1, const float* __restrict__ stats1,
    const float* __restrict__ g1, const float* __restrict__ bb1,
    const ushort_t* __restrict__ bswz2, const float* __restrict__ b2,
    float* __restrict__ outf, float* __restrict__ stats2, float invN)
{
  __shared__ ushort_t As[64 * 128];   // zin staging (16 KB)
  __shared__ ushort_t Bs[64 * 256];   // post-BN1 z1 tile (32 KB)
  __shared__ float sc1[256], sh1[256];
  int tid = threadIdx.x;
  int wave = tid >> 6, lane = tid & 63;
  int lr = lane & 31, half = lane >> 5;
  int row0 = blockIdx.x * 64;
  {
    int c = tid;
    float mu = stats1[c] * invN;
    float var = stats1[256 + c] * invN - mu * mu;
    float r = rsqrtf(var + 1e-5f) * g1[c];
    sc1[c] = r;
    sh1[c] = bb1[c] - mu * r + b1[c] * r;   // fold bias1 into shift
  }
  {
    const uint2* src = (const uint2*)(in + (size_t)row0 * 128);
#pragma unroll
    for (int i = 0; i < 8; ++i) {
      int idx = tid + 256 * i;
      int r = idx >> 5, c = (idx & 31) * 4;
      uint2 v = src[idx];
      int scol = (((c >> 3) ^ (r & 15)) << 3) | (c & 7);
      *(uint2*)&As[r * 128 + scol] = v;
    }
  }
  __syncthreads();
  int nt0 = wave * 2, nt1 = nt0 + 1;
  f32x16 acc00 = zero16(), acc01 = zero16(), acc10 = zero16(), acc11 = zero16();
  {
    const bf16x8* Bp = (const bf16x8*)bswz1;
#pragma unroll
    for (int s = 0; s < 8; ++s) {
      int k = s * 16 + half * 8;
      int scol = ((k >> 3) ^ (lr & 15)) << 3;
      bf16x8 a0 = *(const bf16x8*)&As[lr * 128 + scol];
      bf16x8 a1 = *(const bf16x8*)&As[(32 + lr) * 128 + scol];
      bf16x8 b0v = Bp[(s * 8 + nt0) * 64 + lane];
      bf16x8 b1v = Bp[(s * 8 + nt1) * 64 + lane];
      acc00 = MFMA32(a0, b0v, acc00);
      acc10 = MFMA32(a1, b0v, acc10);
      acc01 = MFMA32(a0, b1v, acc01);
      acc11 = MFMA32(a1, b1v, acc11);
    }
  }
  {
    int col0 = nt0 * 32 + lr, col1 = nt1 * 32 + lr;
    float sc0v = sc1[col0], sh0v = sh1[col0];
    float sc1v = sc1[col1], sh1v = sh1[col1];
    auto wr = [&](const f32x16& a, int mtb, int col, float scv, float shv) {
#pragma unroll
      for (int r2 = 0; r2 < 16; ++r2) {
        int row = mtb + (r2 & 3) + 8 * (r2 >> 2) + 4 * half;
        float v = fmaxf(fmaf(a[r2], scv, shv), 0.f);
        int scol = (((col >> 3) ^ (row & 15)) << 3) | (col & 7);
        Bs[row * 256 + scol] = f2bf(v);
      }
    };
    wr(acc00, 0, col0, sc0v, sh0v);
    wr(acc10, 32, col0, sc0v, sh0v);
    wr(acc01, 0, col1, sc1v, sh1v);
    wr(acc11, 32, col1, sc1v, sh1v);
  }
  __syncthreads();
  f32x16 acc0 = zero16(), acc1 = zero16();
  {
    const bf16x8* Bp2 = (const bf16x8*)bswz2;
#pragma unroll
    for (int s = 0; s < 16; ++s) {
      int k = s * 16 + half * 8;
      int scol = ((k >> 3) ^ (lr & 15)) << 3;
      bf16x8 a0 = *(const bf16x8*)&Bs[lr * 256 + scol];
      bf16x8 a1 = *(const bf16x8*)&Bs[(32 + lr) * 256 + scol];
      bf16x8 b = Bp2[(s * 4 + wave) * 64 + lane];
      acc0 = MFMA32(a0, b, acc0);
      acc1 = MFMA32(a1, b, acc1);
    }
  }
  int col = wave * 32 + lr;
  float bv = b2[col];
  float s0 = 0, q0 = 0;
  auto emit = [&](const f32x16& a, int mtb) {
#pragma unroll
    for (int r2 = 0; r2 < 16; ++r2) {
      int row = row0 + mtb + (r2 & 3) + 8 * (r2 >> 2) + 4 * half;
      float v = a[r2] + bv;
      outf[(size_t)row * 128 + col] = v;
      s0 += v;
      q0 += v * v;
    }
  };
  emit(acc0, 0);
  emit(acc1, 32);
  s0 += __shfl_xor(s0, 32);
  q0 += __shfl_xor(q0, 32);
  if (lane < 32) {
    atomicAdd(&stats2[col], s0);
    atomicAdd(&stats2[128 + col], q0);
  }
}

// Final projection: BN(stats2) on fp32 raw at load (no relu), then
// [64,128]@[128,256]+linb -> fp32 out.
__global__ __launch_bounds__(256) void final_proj_k(
    const float* __restrict__ inf, const ushort_t* __restrict__ bswz,
    const float* __restrict__ bias, const float* __restrict__ stats2,
    const float* __restrict__ g, const float* __restrict__ bb,
    float* __restrict__ outf, float invN)
{
  __shared__ ushort_t As[64 * 128];
  __shared__ float sc[128], sh[128];
  int tid = threadIdx.x;
  int wave = tid >> 6, lane = tid & 63;
  int lr = lane & 31, half = lane >> 5;
  int row0 = blockIdx.x * 64;
  if (tid < 128) {
    int c = tid;
    float mu = stats2[c] * invN;
    float var = stats2[128 + c] * invN - mu * mu;
    float r = rsqrtf(var + 1e-5f) * g[c];
    sc[c] = r;
    sh[c] = bb[c] - mu * r;
  }
  __syncthreads();
  {
    const float4* src = (const float4*)(inf + (size_t)row0 * 128);
#pragma unroll
    for (int i = 0; i < 8; ++i) {
      int idx = tid + 256 * i;
      int r = idx >> 5, c = (idx & 31) * 4;
      float4 v = src[idx];
      v.x = fmaf(v.x, sc[c], sh[c]);
      v.y = fmaf(v.y, sc[c + 1], sh[c + 1]);
      v.z = fmaf(v.z, sc[c + 2], sh[c + 2]);
      v.w = fmaf(v.w, sc[c + 3], sh[c + 3]);
      uint2 o;
      o.x = pack2(v.x, v.y);
      o.y = pack2(v.z, v.w);
      int scol = (((c >> 3) ^ (r & 15)) << 3) | (c & 7);
      *(uint2*)&As[r * 128 + scol] = o;
    }
  }
  __syncthreads();
  int nt0 = wave * 2, nt1 = nt0 + 1;
  f32x16 acc00 = zero16(), acc01 = zero16(), acc10 = zero16(), acc11 = zero16();
  const bf16x8* Bp = (const bf16x8*)bswz;
#pragma unroll
  for (int s = 0; s < 8; ++s) {
    int k = s * 16 + half * 8;
    int scol = ((k >> 3) ^ (lr & 15)) << 3;
    bf16x8 a0 = *(const bf16x8*)&As[lr * 128 + scol];
    bf16x8 a1 = *(const bf16x8*)&As[(32 + lr) * 128 + scol];
    bf16x8 b0 = Bp[(s * 8 + nt0) * 64 + lane];
    bf16x8 b1 = Bp[(s * 8 + nt1) * 64 + lane];
    acc00 = MFMA32(a0, b0, acc00);
    acc10 = MFMA32(a1, b0, acc10);
    acc01 = MFMA32(a0, b1, acc01);
    acc11 = MFMA32(a1, b1, acc11);
  }
  int col0 = nt0 * 32 + lr, col1 = nt1 * 32 + lr;
  float bv0 = bias[col0], bv1 = bias[col1];
  auto emit = [&](const f32x16& a, int mtb, int col, float bv) {
#pragma unroll
    for (int r2 = 0; r2 < 16; ++r2) {
      int row = row0 + mtb + (r2 & 3) + 8 * (r2 >> 2) + 4 * half;
      outf[(size_t)row * 256 + col] = a[r2] + bv;
    }
  };
  emit(acc00, 0, col0, bv0);
  emit(acc10, 32, col0, bv0);
  emit(acc01, 0, col1, bv1);
  emit(acc11, 32, col1, bv1);
}

extern "C" void kernel_launch(void* const* d_in, const int* in_sizes, int n_in,
                              void* d_out, int out_size, void* d_ws, size_t ws_size,
                              hipStream_t stream)
{
  const int* x = (const int*)d_in[0];
  const int* ei = (const int*)d_in[1];
  const int* ea = (const int*)d_in[2];
  const float* aemb = (const float*)d_in[3];
  const float* bemb = (const float*)d_in[4];
  const float* eps = (const float*)d_in[5];
  const float* w1 = (const float*)d_in[6];
  const float* b1 = (const float*)d_in[7];
  const float* bn1g = (const float*)d_in[8];
  const float* bn1b = (const float*)d_in[9];
  const float* w2 = (const float*)d_in[10];
  const float* b2 = (const float*)d_in[11];
  const float* bng = (const float*)d_in[12];
  const float* bnb = (const float*)d_in[13];
  const float* linw = (const float*)d_in[14];
  const float* linb = (const float*)d_in[15];
  int N = in_sizes[0] / 9;   // 40000
  int E = in_sizes[1] / 2;   // 640000
  int nb = (N + 255) / 256;

  char* ws = (char*)d_ws;
  size_t off = 0;
  auto alloc = [&](size_t bytes) {
    void* p = ws + off;
    off += (bytes + 255) & ~(size_t)255;
    return p;
  };
  float* raw = (float*)alloc((size_t)N * 128 * 4);         // pre-BN h, fp32
  ushort_t* zin = (ushort_t*)alloc((size_t)N * 128 * 2);   // GEMM1 input, bf16
  ushort_t* comb = (ushort_t*)alloc((size_t)5 * 4096 * 128 * 2);
  ushort_t* bswz1 = (ushort_t*)alloc((size_t)6 * 32768 * 2);  // 5x w1 + linw
  ushort_t* bswz2 = (ushort_t*)alloc((size_t)5 * 32768 * 2);
  uint32_t* sorted = (uint32_t*)alloc((size_t)E * 4);
  int* rs = (int*)alloc((size_t)(N + 1) * 4);
  int* cursor = (int*)alloc((size_t)N * 4);
  int* cnt = (int*)alloc((size_t)N * 4);
  int* bsum = (int*)alloc((size_t)nb * 4);
  float* stats = (float*)alloc(768 * 4);  // [sum1:256][sq1:256][sum2:128][sq2:128]
  float invN = 1.f / (float)N;

  bond_comb_k<<<(5 * 4096 * 64 + 255) / 256, 256, 0, stream>>>(bemb, comb);
  swz_all_k<<<(11 * 4096 + 255) / 256, 256, 0, stream>>>(w1, linw, w2, bswz1, bswz2);

  atom_encode_k<<<(N * 64 + 255) / 256, 256, 0, stream>>>(x, aemb, raw, N);
  zero_int_k<<<(N + 255) / 256, 256, 0, stream>>>(cnt, N);
  hist_k<<<(E + 255) / 256, 256, 0, stream>>>(ei, cnt, E);
  block_sum_k<<<nb, 256, 0, stream>>>(cnt, bsum, N);
  scan_bsum_k<<<1, 256, 0, stream>>>(bsum, rs + N, nb);
  scan_write_k<<<nb, 256, 0, stream>>>(cnt, bsum, rs, cursor, N);
  scatter_k<<<(E + 255) / 256, 256, 0, stream>>>(ei, ea, cursor, sorted, E);

  for (int l = 0; l < 5; ++l) {
    const float* st2 = (l == 0) ? nullptr : stats + 512;
    const float* gg  = (l == 0) ? nullptr : bng + (size_t)(l - 1) * 128;
    const float* bbb = (l == 0) ? nullptr : bnb + (size_t)(l - 1) * 128;
    aggregate_k<<<(N + 3) / 4, 256, 0, stream>>>(
        raw, comb, sorted, rs, eps, l, zin, stats, st2, gg, bbb, invN, N);
    gemm1_stats_k<<<N / 64, 256, 0, stream>>>(
        zin, bswz1 + (size_t)l * 32768, b1 + (size_t)l * 256,
        stats, stats + 512);
    fused_mlp_k<<<N / 64, 256, 0, stream>>>(
        zin, bswz1 + (size_t)l * 32768, b1 + (size_t)l * 256,
        stats, bn1g + (size_t)l * 256, bn1b + (size_t)l * 256,
        bswz2 + (size_t)l * 32768, b2 + (size_t)l * 128,
        raw, stats + 512, invN);
  }
  final_proj_k<<<N / 64, 256, 0, stream>>>(
      raw, bswz1 + (size_t)5 * 32768, linb, stats + 512,
      bng + (size_t)4 * 128, bnb + (size_t)4 * 128, (float*)d_out, invN);
}